// Round 1
// baseline (259.455 us; speedup 1.0000x reference)
//
#include <hip/hip_runtime.h>

#define NP 128

// One wave (64 lanes) per ray. Lane i owns samples 2i and 2i+1 (float2 loads,
// fully coalesced). Exclusive cumprod over 128 samples = per-lane pair product
// + 6-step shfl_up inclusive scan + shift.
__global__ __launch_bounds__(256) void calc_ray_color_kernel(
    const float* __restrict__ rgb,      // [3, NR, NP]
    const float* __restrict__ density,  // [NR, NP]
    const float* __restrict__ dists,    // [NR, NP]
    const float* __restrict__ zvals,    // [NR, NP]
    float* __restrict__ out,            // rgb_res[3*NR] | bg[NR] | depth[NR] | weight[NR*NP]
    int NR)
{
    const int lane = threadIdx.x & 63;
    const int ray  = (blockIdx.x << 2) + (threadIdx.x >> 6);
    if (ray >= NR) return;

    const size_t base = (size_t)ray * NP + 2 * lane;

    float2 den = *(const float2*)(density + base);
    float2 dst = *(const float2*)(dists + base);

    float a0 = 1.0f - __expf(-den.x * dst.x);
    float a1 = 1.0f - __expf(-den.y * dst.y);
    float x0 = 1.0f - a0 + 1e-10f;
    float x1 = 1.0f - a1 + 1e-10f;

    // inclusive prefix product of per-lane pair products across the wave
    float p = x0 * x1;
    #pragma unroll
    for (int off = 1; off < 64; off <<= 1) {
        float v = __shfl_up(p, off);
        if (lane >= off) p *= v;
    }
    // exclusive
    float excl = __shfl_up(p, 1);
    if (lane == 0) excl = 1.0f;

    const float t0 = excl;
    const float t1 = excl * x0;
    const float w0 = a0 * t0;
    const float w1 = a1 * t1;

    // weight out (after the 5*NR scalar outputs)
    *(float2*)(out + (size_t)5 * NR + base) = make_float2(w0, w1);

    float2 z = *(const float2*)(zvals + base);
    float sdep = w0 * z.x + w1 * z.y;
    float sacc = w0 + w1;

    const float* rgb_ray = rgb + base;
    const size_t cstride = (size_t)NR * NP;
    float2 c0 = *(const float2*)(rgb_ray);
    float2 c1 = *(const float2*)(rgb_ray + cstride);
    float2 c2 = *(const float2*)(rgb_ray + 2 * cstride);
    float s0 = w0 * c0.x + w1 * c0.y;
    float s1 = w0 * c1.x + w1 * c1.y;
    float s2 = w0 * c2.x + w1 * c2.y;

    // wave reductions
    #pragma unroll
    for (int off = 32; off >= 1; off >>= 1) {
        s0   += __shfl_down(s0, off);
        s1   += __shfl_down(s1, off);
        s2   += __shfl_down(s2, off);
        sdep += __shfl_down(sdep, off);
        sacc += __shfl_down(sacc, off);
    }

    if (lane == 0) {
        out[ray]              = s0;
        out[(size_t)NR + ray] = s1;
        out[2 * (size_t)NR + ray] = s2;
        out[3 * (size_t)NR + ray] = 1.0f - sacc;
        out[4 * (size_t)NR + ray] = sdep;
    }
}

extern "C" void kernel_launch(void* const* d_in, const int* in_sizes, int n_in,
                              void* d_out, int out_size, void* d_ws, size_t ws_size,
                              hipStream_t stream) {
    // d_in[0] = fg_vps  (UNUSED by reference — do not read)
    const float* rgb     = (const float*)d_in[1];
    const float* density = (const float*)d_in[2];
    const float* dists   = (const float*)d_in[3];
    const float* zvals   = (const float*)d_in[4];
    float* out = (float*)d_out;

    const int NR = in_sizes[2] / NP;   // density is [1,1,NR,NP]
    const int rays_per_block = 4;      // 256 threads = 4 waves
    const int grid = (NR + rays_per_block - 1) / rays_per_block;

    calc_ray_color_kernel<<<grid, 256, 0, stream>>>(rgb, density, dists, zvals, out, NR);
}